// Round 1
// baseline (379.069 us; speedup 1.0000x reference)
//
#include <hip/hip_runtime.h>

#define HID 10
#define TT  2048
#define BB  4096

__device__ __forceinline__ float fast_tanh(float x) {
    // tanh(x) = 1 - 2/(exp2(x * 2*log2(e)) + 1); saturates correctly at +-inf
#if __has_builtin(__builtin_amdgcn_exp2f)
    float e = __builtin_amdgcn_exp2f(x * 2.885390081777926814f);
#else
    float e = exp2f(x * 2.885390081777926814f);
#endif
#if __has_builtin(__builtin_amdgcn_rcpf)
    float r = __builtin_amdgcn_rcpf(e + 1.0f);
#else
    float r = 1.0f / (e + 1.0f);
#endif
    return fmaf(-2.0f, r, 1.0f);
}

// 16 lanes per batch row (lane = hidden-unit index, 10 active, 6 spare),
// 4 rows per wave, 1 wave per block -> 1024 blocks = 1 wave/SIMD chip-wide.
__global__ void __launch_bounds__(64) rnn_kernel(
    const float* __restrict__ x,    const float* __restrict__ hs,
    const float* __restrict__ Wih0, const float* __restrict__ Whh0,
    const float* __restrict__ bih0, const float* __restrict__ bhh0,
    const float* __restrict__ Wih1, const float* __restrict__ Whh1,
    const float* __restrict__ bih1, const float* __restrict__ bhh1,
    const float* __restrict__ Wout, const float* __restrict__ boutp,
    float* __restrict__ out)
{
    const int tid  = threadIdx.x;
    const int lane = tid & 15;          // hidden unit index
    const int grp  = tid >> 4;          // 0..3 row-within-wave
    const int row  = blockIdx.x * 4 + grp;

    // per-row 48-float region: [0..15]=h0 slots, [16..31]=h1 slots, rest pad.
    // stride 48 floats => group bases 16 banks apart: reads/writes are <=2-way
    // bank aliased (free per m136).
    __shared__ float lds[4 * 48];
    float* hbuf = &lds[grp * 48];

    // ---- per-lane weight rows (lanes >= HID get zeros; never read back) ----
    float whh0[HID], wih1[HID], whh1[HID], wout[HID];
    float wih0i, b0c, b1c;
    if (lane < HID) {
        #pragma unroll
        for (int j = 0; j < HID; ++j) {
            whh0[j] = Whh0[lane * HID + j];
            wih1[j] = Wih1[lane * HID + j];
            whh1[j] = Whh1[lane * HID + j];
        }
        wih0i = Wih0[lane];
        b0c   = bih0[lane] + bhh0[lane];
        b1c   = bih1[lane] + bhh1[lane];
    } else {
        #pragma unroll
        for (int j = 0; j < HID; ++j) { whh0[j] = 0.f; wih1[j] = 0.f; whh1[j] = 0.f; }
        wih0i = 0.f; b0c = 0.f; b1c = 0.f;
    }
    #pragma unroll
    for (int j = 0; j < HID; ++j) wout[j] = Wout[j];
    const float bo = boutp[0];

    // ---- initial state: every lane holds the full h0/h1 vectors ----
    float h0v[HID], h1v[HID];
    #pragma unroll
    for (int j = 0; j < HID; ++j) {
        h0v[j] = hs[row * HID + j];
        h1v[j] = hs[BB * HID + row * HID + j];
    }

    const float* xrow = x   + (size_t)row * TT;
    float*       orow = out + (size_t)row * TT;

    // software-pipelined x prefetch (one 8-step body ahead)
    float4 xa = *(const float4*)(xrow);
    float4 xb = *(const float4*)(xrow + 4);

    float h0n = 0.f, h1n = 0.f;

    for (int t0 = 0; t0 < TT; t0 += 8) {
        int tp = t0 + 8; tp = (tp > TT - 8) ? (TT - 8) : tp;   // clamped prefetch
        float4 xc = *(const float4*)(xrow + tp);
        float4 xd = *(const float4*)(xrow + tp + 4);

        float xw[8] = {xa.x, xa.y, xa.z, xa.w, xb.x, xb.y, xb.z, xb.w};
        float o[8];

        #pragma unroll
        for (int k = 0; k < 8; ++k) {
            // ---------- layer 0 ----------
            float a0 = fmaf(xw[k], wih0i, b0c), a0b = 0.f;   // two chains
            #pragma unroll
            for (int j = 0; j < HID; j += 2) {
                a0  = fmaf(whh0[j],   h0v[j],   a0);
                a0b = fmaf(whh0[j+1], h0v[j+1], a0b);
            }
            h0n = fast_tanh(a0 + a0b);
            hbuf[lane] = h0n;
            __builtin_amdgcn_wave_barrier();
            const float4 p0 = *(const float4*)&hbuf[0];
            const float4 p1 = *(const float4*)&hbuf[4];
            const float2 p2 = *(const float2*)&hbuf[8];
            // layer-1 old-h1 half first: fills the LDS read latency
            float a1 = b1c, a1b = 0.f;
            #pragma unroll
            for (int j = 0; j < HID; j += 2) {
                a1  = fmaf(whh1[j],   h1v[j],   a1);
                a1b = fmaf(whh1[j+1], h1v[j+1], a1b);
            }
            h0v[0]=p0.x; h0v[1]=p0.y; h0v[2]=p0.z; h0v[3]=p0.w;
            h0v[4]=p1.x; h0v[5]=p1.y; h0v[6]=p1.z; h0v[7]=p1.w;
            h0v[8]=p2.x; h0v[9]=p2.y;
            #pragma unroll
            for (int j = 0; j < HID; j += 2) {
                a1  = fmaf(wih1[j],   h0v[j],   a1);
                a1b = fmaf(wih1[j+1], h0v[j+1], a1b);
            }
            h1n = fast_tanh(a1 + a1b);
            hbuf[16 + lane] = h1n;
            __builtin_amdgcn_wave_barrier();
            const float4 q0 = *(const float4*)&hbuf[16];
            const float4 q1 = *(const float4*)&hbuf[20];
            const float2 q2 = *(const float2*)&hbuf[24];
            h1v[0]=q0.x; h1v[1]=q0.y; h1v[2]=q0.z; h1v[3]=q0.w;
            h1v[4]=q1.x; h1v[5]=q1.y; h1v[6]=q1.z; h1v[7]=q1.w;
            h1v[8]=q2.x; h1v[9]=q2.y;
            // ---------- fused output linear ----------
            float ov = bo, ovb = 0.f;
            #pragma unroll
            for (int j = 0; j < HID; j += 2) {
                ov  = fmaf(wout[j],   h1v[j],   ov);
                ovb = fmaf(wout[j+1], h1v[j+1], ovb);
            }
            o[k] = ov + ovb;
        }

        if (lane == 0) {
            *(float4*)(orow + t0)     = make_float4(o[0], o[1], o[2], o[3]);
            *(float4*)(orow + t0 + 4) = make_float4(o[4], o[5], o[6], o[7]);
        }
        xa = xc; xb = xd;
    }

    // final hidden state: [2, B, H] appended after the B*T outputs
    if (lane < HID) {
        out[(size_t)BB * TT + (size_t)row * HID + lane]                     = h0n;
        out[(size_t)BB * TT + (size_t)BB * HID + (size_t)row * HID + lane]  = h1n;
    }
}

extern "C" void kernel_launch(void* const* d_in, const int* in_sizes, int n_in,
                              void* d_out, int out_size, void* d_ws, size_t ws_size,
                              hipStream_t stream) {
    const float* x    = (const float*)d_in[0];
    const float* hs   = (const float*)d_in[1];
    const float* Wih0 = (const float*)d_in[2];
    const float* Whh0 = (const float*)d_in[3];
    const float* bih0 = (const float*)d_in[4];
    const float* bhh0 = (const float*)d_in[5];
    const float* Wih1 = (const float*)d_in[6];
    const float* Whh1 = (const float*)d_in[7];
    const float* bih1 = (const float*)d_in[8];
    const float* bhh1 = (const float*)d_in[9];
    const float* Wout = (const float*)d_in[10];
    const float* bout = (const float*)d_in[11];
    float* out = (float*)d_out;

    dim3 grid(BB / 4), block(64);
    hipLaunchKernelGGL(rnn_kernel, grid, block, 0, stream,
        x, hs, Wih0, Whh0, bih0, bhh0, Wih1, Whh1, bih1, bhh1, Wout, bout, out);
}